// Round 3
// baseline (407.321 us; speedup 1.0000x reference)
//
#include <hip/hip_runtime.h>

#define NN 100000
#define DD 128
#define EE 640000
#define NPAD 100352  // NN rounded up to 256 multiple

typedef __bf16 bf16x8 __attribute__((ext_vector_type(8)));
typedef float floatx4 __attribute__((ext_vector_type(4)));

union BF8 {
    bf16x8 v;
    unsigned short u[8];
    int4 i4;
};

__device__ __forceinline__ unsigned short f2bf(float f) {
    unsigned int u = __float_as_uint(f);
    u += 0x7FFF + ((u >> 16) & 1);   // round-to-nearest-even
    return (unsigned short)(u >> 16);
}

// ---------------------------------------------------------------------------
// CSR build: histogram -> 3-kernel exclusive scan -> bucket scatter
// ---------------------------------------------------------------------------
__global__ __launch_bounds__(256) void hist_k(const int* __restrict__ ei,
                                              int* __restrict__ deg) {
    int e = blockIdx.x * 256 + threadIdx.x;
    if (e < EE) atomicAdd(&deg[ei[EE + e]], 1);
}

__global__ __launch_bounds__(256) void scan1_k(const int* __restrict__ deg,
                                               int* __restrict__ exc,
                                               int* __restrict__ chunkSums) {
    __shared__ int s[256];
    int t = threadIdx.x, g = blockIdx.x * 256 + t;
    int v = (g < NN) ? deg[g] : 0;
    s[t] = v;
    __syncthreads();
    for (int off = 1; off < 256; off <<= 1) {
        int u = (t >= off) ? s[t - off] : 0;
        __syncthreads();
        s[t] += u;
        __syncthreads();
    }
    if (g < NN) exc[g] = s[t] - v;
    if (t == 255) chunkSums[blockIdx.x] = s[255];
}

__global__ __launch_bounds__(512) void scan2_k(int* __restrict__ chunkSums, int n) {
    __shared__ int s[512];
    int t = threadIdx.x;
    int v = (t < n) ? chunkSums[t] : 0;
    s[t] = v;
    __syncthreads();
    for (int off = 1; off < 512; off <<= 1) {
        int u = (t >= off) ? s[t - off] : 0;
        __syncthreads();
        s[t] += u;
        __syncthreads();
    }
    if (t < n) chunkSums[t] = s[t] - v;  // exclusive
}

__global__ __launch_bounds__(256) void scan3_k(int* __restrict__ exc,
                                               const int* __restrict__ chunkSums,
                                               int* __restrict__ cursor) {
    int g = blockIdx.x * 256 + threadIdx.x;
    if (g < NN) {
        int o = exc[g] + chunkSums[blockIdx.x];
        exc[g] = o;
        cursor[g] = o;
    }
}

__global__ __launch_bounds__(256) void esort_k(const int* __restrict__ ei,
                                               int* __restrict__ cursor,
                                               int* __restrict__ ssrc) {
    int e = blockIdx.x * 256 + threadIdx.x;
    if (e >= EE) return;
    int pos = atomicAdd(&cursor[ei[EE + e]], 1);
    ssrc[pos] = ei[e];
}

// ---------------------------------------------------------------------------
// W fp32 -> bf16 preconvert (both layers, once). 32 blocks, ~2 us.
// ---------------------------------------------------------------------------
__global__ __launch_bounds__(256) void wconv_k(const float* __restrict__ W1,
                                               const float* __restrict__ W2,
                                               unsigned short* __restrict__ wb) {
    int i = blockIdx.x * 256 + threadIdx.x;  // float4 units, 0..8191
    const float4* s4 = (i < 4096) ? (const float4*)W1 : (const float4*)W2;
    float4 v = s4[i & 4095];
    ushort4 u;
    u.x = f2bf(v.x); u.y = f2bf(v.y); u.z = f2bf(v.z); u.w = f2bf(v.w);
    ((ushort4*)wb)[i] = u;
}

// ---------------------------------------------------------------------------
// aggregate + fuse: h[node] = bf16((1+eps)*x[node] + sum_{src in CSR} x[src])
// 32 lanes (float4) per node; 4-wide predicated gather unroll for MLP.
// ---------------------------------------------------------------------------
__global__ __launch_bounds__(256) void aggregate_k(
    const float4* __restrict__ x4, const int* __restrict__ ssrc,
    const int* __restrict__ offs, const int* __restrict__ deg,
    const float* __restrict__ epsp, ushort4* __restrict__ hout) {
    int tid = blockIdx.x * 256 + threadIdx.x;
    int node = tid >> 5, lane = tid & 31;
    if (node >= NN) return;
    int start = offs[node], d = deg[node];
    float ef = 1.0f + epsp[0];
    float4 v = x4[node * 32 + lane];
    float ax = ef * v.x, ay = ef * v.y, az = ef * v.z, aw = ef * v.w;
    for (int j = 0; j < d; j += 4) {
        int r = d - j;          // >= 1
        int b = start + j;
        int s0 = ssrc[b];
        int s1 = ssrc[b + ((r > 1) ? 1 : 0)];
        int s2 = ssrc[b + ((r > 2) ? 2 : 0)];
        int s3 = ssrc[b + ((r > 3) ? 3 : 0)];
        float4 xa = x4[s0 * 32 + lane];
        float4 xb = x4[s1 * 32 + lane];
        float4 xc = x4[s2 * 32 + lane];
        float4 xd = x4[s3 * 32 + lane];
        float m1 = (r > 1) ? 1.f : 0.f;
        float m2 = (r > 2) ? 1.f : 0.f;
        float m3 = (r > 3) ? 1.f : 0.f;
        ax += xa.x; ay += xa.y; az += xa.z; aw += xa.w;
        ax += m1 * xb.x; ay += m1 * xb.y; az += m1 * xb.z; aw += m1 * xb.w;
        ax += m2 * xc.x; ay += m2 * xc.y; az += m2 * xc.z; aw += m2 * xc.w;
        ax += m3 * xd.x; ay += m3 * xd.y; az += m3 * xd.z; aw += m3 * xd.w;
    }
    ushort4 u;
    u.x = f2bf(ax); u.y = f2bf(ay); u.z = f2bf(az); u.w = f2bf(aw);
    hout[node * 32 + lane] = u;
}

// ---------------------------------------------------------------------------
// LDS-free fused GEMM + bias + BN-stat accumulation.
// 64 rows/block (one 16-row stripe per wave) -> grid 1563 = ~6 blocks/CU,
// ~24 resident waves/CU to hide global-load latency (was 782 blocks / ~12
// waves/CU -> latency-bound at 21% occupancy, VALUBusy 6%).
// A fragments straight from global (consumed once, no reuse); B fragments
// straight from bf16 W (32 KB, L1/L2-resident broadcast).
// FUSE_BN=1: A = fp32 yin with BN(statsIn,g,beta)+ReLU applied in the loader.
// ---------------------------------------------------------------------------
template <int FUSE_BN>
__global__ __launch_bounds__(256, 6) void gin_gemm_k(
    const unsigned short* __restrict__ hin,
    const float* __restrict__ yin,
    const float* __restrict__ statsIn,
    const float* __restrict__ gmm,
    const float* __restrict__ bta,
    const unsigned short* __restrict__ Wbf, const float* __restrict__ bias,
    float* __restrict__ y, float* __restrict__ statsOut) {
    __shared__ __align__(16) float s_sum[128];
    __shared__ __align__(16) float s_sq[128];
    __shared__ __align__(16) float sc[128];
    __shared__ __align__(16) float sh[128];

    const int tid = threadIdx.x;
    const int rowBase = blockIdx.x * 64;
    const int l = tid & 63, w = tid >> 6;
    const int m = l & 15, q = l >> 4;

    if (tid < 128) {
        s_sum[tid] = 0.f;
        s_sq[tid] = 0.f;
        if (FUSE_BN) {
            const float inv = 1.0f / (float)NN;
            float mean = statsIn[tid] * inv;
            float var = statsIn[128 + tid] * inv - mean * mean;
            float s = gmm[tid] * rsqrtf(var + 1e-5f);
            sc[tid] = s;
            sh[tid] = bta[tid] - mean * s;
        }
    }
    __syncthreads();

    // --- A fragments: row rowBase + w*16 + m, k = kc*32 + q*8 ---
    bf16x8 a[4];
    {
        int rg = rowBase + w * 16 + m;
        bool ok = rg < NN;
        if (FUSE_BN) {
            const float* yr = yin + (size_t)rg * 128;
#pragma unroll
            for (int kc = 0; kc < 4; ++kc) {
                int k0 = kc * 32 + q * 8;
                float4 v0 = make_float4(0.f, 0.f, 0.f, 0.f), v1 = v0;
                if (ok) {
                    v0 = *(const float4*)(yr + k0);
                    v1 = *(const float4*)(yr + k0 + 4);
                }
                float4 s0 = *(const float4*)(sc + k0);
                float4 s1 = *(const float4*)(sc + k0 + 4);
                float4 h0 = *(const float4*)(sh + k0);
                float4 h1 = *(const float4*)(sh + k0 + 4);
                BF8 t;
                t.u[0] = f2bf(fmaxf(v0.x * s0.x + h0.x, 0.f));
                t.u[1] = f2bf(fmaxf(v0.y * s0.y + h0.y, 0.f));
                t.u[2] = f2bf(fmaxf(v0.z * s0.z + h0.z, 0.f));
                t.u[3] = f2bf(fmaxf(v0.w * s0.w + h0.w, 0.f));
                t.u[4] = f2bf(fmaxf(v1.x * s1.x + h1.x, 0.f));
                t.u[5] = f2bf(fmaxf(v1.y * s1.y + h1.y, 0.f));
                t.u[6] = f2bf(fmaxf(v1.z * s1.z + h1.z, 0.f));
                t.u[7] = f2bf(fmaxf(v1.w * s1.w + h1.w, 0.f));
                a[kc] = t.v;
            }
        } else {
            const unsigned short* ar = hin + (size_t)rg * 128;
#pragma unroll
            for (int kc = 0; kc < 4; ++kc) {
                BF8 t;
                if (ok) t.i4 = *(const int4*)(ar + kc * 32 + q * 8);
                else    t.i4 = make_int4(0, 0, 0, 0);
                a[kc] = t.v;
            }
        }
    }

    // --- compute: B fragments from cache-resident bf16 W ---
    floatx4 acc[8];
#pragma unroll
    for (int ct = 0; ct < 8; ++ct) acc[ct] = (floatx4)0.0f;

#pragma unroll
    for (int ct = 0; ct < 8; ++ct) {
        const unsigned short* wr = Wbf + (size_t)(ct * 16 + m) * 128;
#pragma unroll
        for (int kc = 0; kc < 4; ++kc) {
            BF8 t;
            t.i4 = *(const int4*)(wr + kc * 32 + q * 8);
            acc[ct] = __builtin_amdgcn_mfma_f32_16x16x32_bf16(a[kc], t.v, acc[ct], 0, 0, 0);
        }
    }

    // epilogue: bias, store y, per-column partial stats (mask padding rows)
#pragma unroll
    for (int ct = 0; ct < 8; ++ct) {
        int col = ct * 16 + m;
        float bc = bias[col];
        float ps = 0.f, pq = 0.f;
#pragma unroll
        for (int i = 0; i < 4; ++i) {
            int rg = rowBase + w * 16 + q * 4 + i;
            if (rg < NN) {
                float yv = acc[ct][i] + bc;
                y[rg * 128 + col] = yv;
                ps += yv;
                pq += yv * yv;
            }
        }
        atomicAdd(&s_sum[col], ps);
        atomicAdd(&s_sq[col], pq);
    }
    __syncthreads();
    if (tid < 128) {
        unsafeAtomicAdd(&statsOut[tid], s_sum[tid]);
        unsafeAtomicAdd(&statsOut[128 + tid], s_sq[tid]);
    }
}

// ---------------------------------------------------------------------------
// BN(train, biased var) + ReLU.  OUT_BF16: write bf16 (h1) else fp32 in place
// ---------------------------------------------------------------------------
template <int OUT_BF16>
__global__ __launch_bounds__(256) void bn_relu_k(
    const float* __restrict__ y, const float* __restrict__ stats,
    const float* __restrict__ g, const float* __restrict__ beta,
    float* outf, unsigned short* __restrict__ outh) {
    __shared__ __align__(16) float sc[128];
    __shared__ __align__(16) float sh[128];
    int t = threadIdx.x;
    if (t < 128) {
        const float inv = 1.0f / (float)NN;
        float mean = stats[t] * inv;
        float var = stats[128 + t] * inv - mean * mean;
        float s = g[t] * rsqrtf(var + 1e-5f);
        sc[t] = s;
        sh[t] = beta[t] - mean * s;
    }
    __syncthreads();
    const int total4 = NN * 32;
    const float4* y4 = (const float4*)y;
    for (int i = blockIdx.x * 256 + t; i < total4; i += gridDim.x * 256) {
        int c4 = i & 31;
        float4 v = y4[i];
        float4 s = ((const float4*)sc)[c4];
        float4 b = ((const float4*)sh)[c4];
        float r0 = fmaxf(v.x * s.x + b.x, 0.f);
        float r1 = fmaxf(v.y * s.y + b.y, 0.f);
        float r2 = fmaxf(v.z * s.z + b.z, 0.f);
        float r3 = fmaxf(v.w * s.w + b.w, 0.f);
        if (OUT_BF16) {
            ushort4 u;
            u.x = f2bf(r0); u.y = f2bf(r1); u.z = f2bf(r2); u.w = f2bf(r3);
            ((ushort4*)outh)[i] = u;
        } else {
            ((float4*)outf)[i] = make_float4(r0, r1, r2, r3);
        }
    }
}

// ---------------------------------------------------------------------------
extern "C" void kernel_launch(void* const* d_in, const int* in_sizes, int n_in,
                              void* d_out, int out_size, void* d_ws, size_t ws_size,
                              hipStream_t stream) {
    const float* x   = (const float*)d_in[0];
    const int* ei    = (const int*)d_in[1];   // int64 in ref -> int32 from harness
    const float* eps = (const float*)d_in[2];
    const float* W1  = (const float*)d_in[3];
    const float* b1  = (const float*)d_in[4];
    const float* g1  = (const float*)d_in[5];
    const float* be1 = (const float*)d_in[6];
    const float* W2  = (const float*)d_in[7];
    const float* b2  = (const float*)d_in[8];
    const float* g2  = (const float*)d_in[9];
    const float* be2 = (const float*)d_in[10];
    float* out = (float*)d_out;

    // Workspace layouts.
    //  fallback (~29.5 MB): [csr 3.77MB][hbuf 25.6MB][stats 2KB]; wbf overlays
    //    the dead deg[] region after aggregate_k.
    //  fused (~77 MB): [ybuf 51.2MB (csr overlaid at front)][hbuf][stats][wbf]
    const size_t csr_bytes  = ((size_t)3 * NPAD + 512 + EE + 256) * 4;
    const size_t ybuf_bytes = (size_t)NN * DD * 4;
    const size_t hbuf_bytes = (size_t)NN * DD * 2;
    const size_t fused_need = ybuf_bytes + hbuf_bytes + 2048 + 65536;
    const bool fused = ws_size >= fused_need;

    int* deg        = (int*)d_ws;           // NPAD
    int* offs       = deg + NPAD;           // NPAD
    int* cursor     = offs + NPAD;          // NPAD
    int* chunkSums  = cursor + NPAD;        // 512
    int* ssrc       = chunkSums + 512;      // EE + pad
    float* ybuf     = (float*)d_ws;         // fused only; CSR is dead by gemm1

    char* hstart = (char*)d_ws + (fused ? ybuf_bytes : csr_bytes);
    unsigned short* hbuf = (unsigned short*)hstart;
    float* stats = (float*)(hstart + hbuf_bytes);
    unsigned short* wbf = fused ? (unsigned short*)(stats + 512)
                                : (unsigned short*)deg;  // deg dead post-aggregate

    hipMemsetAsync(deg, 0, NPAD * sizeof(int), stream);
    hipMemsetAsync(stats, 0, 512 * sizeof(float), stream);

    const int numChunks = (NN + 255) / 256;  // 391
    hist_k<<<(EE + 255) / 256, 256, 0, stream>>>(ei, deg);
    scan1_k<<<numChunks, 256, 0, stream>>>(deg, offs, chunkSums);
    scan2_k<<<1, 512, 0, stream>>>(chunkSums, numChunks);
    scan3_k<<<numChunks, 256, 0, stream>>>(offs, chunkSums, cursor);
    esort_k<<<(EE + 255) / 256, 256, 0, stream>>>(ei, cursor, ssrc);
    aggregate_k<<<(NN * 32 + 255) / 256, 256, 0, stream>>>(
        (const float4*)x, ssrc, offs, deg, eps, (ushort4*)hbuf);
    wconv_k<<<32, 256, 0, stream>>>(W1, W2, wbf);  // after aggregate: deg is dead

    int gblocks = (NN + 63) / 64;  // 1563
    if (fused) {
        gin_gemm_k<0><<<gblocks, 256, 0, stream>>>(
            hbuf, nullptr, nullptr, nullptr, nullptr, wbf, b1, ybuf, stats);
        gin_gemm_k<1><<<gblocks, 256, 0, stream>>>(
            nullptr, ybuf, stats, g1, be1, wbf + 16384, b2, out, stats + 256);
        bn_relu_k<0><<<4096, 256, 0, stream>>>(out, stats + 256, g2, be2, out, nullptr);
    } else {
        gin_gemm_k<0><<<gblocks, 256, 0, stream>>>(
            hbuf, nullptr, nullptr, nullptr, nullptr, wbf, b1, out, stats);
        bn_relu_k<1><<<4096, 256, 0, stream>>>(out, stats, g1, be1, nullptr, hbuf);
        gin_gemm_k<0><<<gblocks, 256, 0, stream>>>(
            hbuf, nullptr, nullptr, nullptr, nullptr, wbf + 16384, b2, out, stats + 256);
        bn_relu_k<0><<<4096, 256, 0, stream>>>(out, stats + 256, g2, be2, out, nullptr);
    }
}

// Round 4
// 321.019 us; speedup vs baseline: 1.2688x; 1.2688x over previous
//
#include <hip/hip_runtime.h>

#define NN 100000
#define DD 128
#define EE 640000
#define NPAD 100352  // NN rounded up to 256 multiple

typedef __bf16 bf16x8 __attribute__((ext_vector_type(8)));
typedef float floatx4 __attribute__((ext_vector_type(4)));

union BF8 {
    bf16x8 v;
    unsigned short u[8];
    int4 i4;
};

__device__ __forceinline__ unsigned short f2bf(float f) {
    unsigned int u = __float_as_uint(f);
    u += 0x7FFF + ((u >> 16) & 1);   // round-to-nearest-even
    return (unsigned short)(u >> 16);
}

// ---------------------------------------------------------------------------
// CSR build: histogram -> 3-kernel exclusive scan -> bucket scatter
// ---------------------------------------------------------------------------
__global__ __launch_bounds__(256) void hist_k(const int* __restrict__ ei,
                                              int* __restrict__ deg) {
    int e = blockIdx.x * 256 + threadIdx.x;
    if (e < EE) atomicAdd(&deg[ei[EE + e]], 1);
}

__global__ __launch_bounds__(256) void scan1_k(const int* __restrict__ deg,
                                               int* __restrict__ exc,
                                               int* __restrict__ chunkSums) {
    __shared__ int s[256];
    int t = threadIdx.x, g = blockIdx.x * 256 + t;
    int v = (g < NN) ? deg[g] : 0;
    s[t] = v;
    __syncthreads();
    for (int off = 1; off < 256; off <<= 1) {
        int u = (t >= off) ? s[t - off] : 0;
        __syncthreads();
        s[t] += u;
        __syncthreads();
    }
    if (g < NN) exc[g] = s[t] - v;
    if (t == 255) chunkSums[blockIdx.x] = s[255];
}

__global__ __launch_bounds__(512) void scan2_k(int* __restrict__ chunkSums, int n) {
    __shared__ int s[512];
    int t = threadIdx.x;
    int v = (t < n) ? chunkSums[t] : 0;
    s[t] = v;
    __syncthreads();
    for (int off = 1; off < 512; off <<= 1) {
        int u = (t >= off) ? s[t - off] : 0;
        __syncthreads();
        s[t] += u;
        __syncthreads();
    }
    if (t < n) chunkSums[t] = s[t] - v;  // exclusive
}

__global__ __launch_bounds__(256) void scan3_k(int* __restrict__ exc,
                                               const int* __restrict__ chunkSums,
                                               int* __restrict__ cursor) {
    int g = blockIdx.x * 256 + threadIdx.x;
    if (g < NN) {
        int o = exc[g] + chunkSums[blockIdx.x];
        exc[g] = o;
        cursor[g] = o;
    }
}

__global__ __launch_bounds__(256) void esort_k(const int* __restrict__ ei,
                                               int* __restrict__ cursor,
                                               int* __restrict__ ssrc) {
    int e = blockIdx.x * 256 + threadIdx.x;
    if (e >= EE) return;
    int pos = atomicAdd(&cursor[ei[EE + e]], 1);
    ssrc[pos] = ei[e];
}

// ---------------------------------------------------------------------------
// W fp32 -> bf16 preconvert (both layers, once). 32 blocks, ~2 us.
// ---------------------------------------------------------------------------
__global__ __launch_bounds__(256) void wconv_k(const float* __restrict__ W1,
                                               const float* __restrict__ W2,
                                               unsigned short* __restrict__ wb) {
    int i = blockIdx.x * 256 + threadIdx.x;  // float4 units, 0..8191
    const float4* s4 = (i < 4096) ? (const float4*)W1 : (const float4*)W2;
    float4 v = s4[i & 4095];
    ushort4 u;
    u.x = f2bf(v.x); u.y = f2bf(v.y); u.z = f2bf(v.z); u.w = f2bf(v.w);
    ((ushort4*)wb)[i] = u;
}

// ---------------------------------------------------------------------------
// aggregate + fuse: h[node] = bf16((1+eps)*x[node] + sum_{src in CSR} x[src])
// 32 lanes (float4) per node; 4-wide predicated gather unroll for MLP.
// ---------------------------------------------------------------------------
__global__ __launch_bounds__(256) void aggregate_k(
    const float4* __restrict__ x4, const int* __restrict__ ssrc,
    const int* __restrict__ offs, const int* __restrict__ deg,
    const float* __restrict__ epsp, ushort4* __restrict__ hout) {
    int tid = blockIdx.x * 256 + threadIdx.x;
    int node = tid >> 5, lane = tid & 31;
    if (node >= NN) return;
    int start = offs[node], d = deg[node];
    float ef = 1.0f + epsp[0];
    float4 v = x4[node * 32 + lane];
    float ax = ef * v.x, ay = ef * v.y, az = ef * v.z, aw = ef * v.w;
    for (int j = 0; j < d; j += 4) {
        int r = d - j;          // >= 1
        int b = start + j;
        int s0 = ssrc[b];
        int s1 = ssrc[b + ((r > 1) ? 1 : 0)];
        int s2 = ssrc[b + ((r > 2) ? 2 : 0)];
        int s3 = ssrc[b + ((r > 3) ? 3 : 0)];
        float4 xa = x4[s0 * 32 + lane];
        float4 xb = x4[s1 * 32 + lane];
        float4 xc = x4[s2 * 32 + lane];
        float4 xd = x4[s3 * 32 + lane];
        float m1 = (r > 1) ? 1.f : 0.f;
        float m2 = (r > 2) ? 1.f : 0.f;
        float m3 = (r > 3) ? 1.f : 0.f;
        ax += xa.x; ay += xa.y; az += xa.z; aw += xa.w;
        ax += m1 * xb.x; ay += m1 * xb.y; az += m1 * xb.z; aw += m1 * xb.w;
        ax += m2 * xc.x; ay += m2 * xc.y; az += m2 * xc.z; aw += m2 * xc.w;
        ax += m3 * xd.x; ay += m3 * xd.y; az += m3 * xd.z; aw += m3 * xd.w;
    }
    ushort4 u;
    u.x = f2bf(ax); u.y = f2bf(ay); u.z = f2bf(az); u.w = f2bf(aw);
    hout[node * 32 + lane] = u;
}

// ---------------------------------------------------------------------------
// Persistent-W GEMM + bias + BN-stat accumulation.
// Each wave holds the ENTIRE bf16 W in registers (32 x bf16x8 = 128 VGPR,
// distributed over 64 lanes) and grid-strides over 16-row A-tiles:
//   loop: {8 independent A loads (prefetched 1 tile ahead)} ->
//         {32 register-only MFMAs, 8 independent acc chains} -> stores.
// No per-tile W traffic (rounds 2/3 re-read 32KB W per tile from L2 — the
// measured latency wall: occupancy rose 13->45% while perf FELL 58->88us).
// NN = 6250 * 16 exactly -> no row masking. Stats accumulate in registers,
// flushed via LDS once per block.
// ---------------------------------------------------------------------------
__global__ __launch_bounds__(256, 2) void gin_gemm_k(
    const unsigned short* __restrict__ hin,
    const unsigned short* __restrict__ Wbf, const float* __restrict__ bias,
    float* __restrict__ y, float* __restrict__ statsOut) {
    __shared__ __align__(16) float s_sum[128];
    __shared__ __align__(16) float s_sq[128];

    const int tid = threadIdx.x;
    const int l = tid & 63, w = tid >> 6;
    const int m = l & 15, q = l >> 4;

    if (tid < 128) { s_sum[tid] = 0.f; s_sq[tid] = 0.f; }

    // --- whole W into registers, once per wave ---
    bf16x8 wf[8][4];
#pragma unroll
    for (int ct = 0; ct < 8; ++ct) {
        const unsigned short* wr = Wbf + (size_t)(ct * 16 + m) * 128 + q * 8;
#pragma unroll
        for (int kc = 0; kc < 4; ++kc) {
            BF8 t;
            t.i4 = *(const int4*)(wr + kc * 32);
            wf[ct][kc] = t.v;
        }
    }
    float bc[8];
#pragma unroll
    for (int ct = 0; ct < 8; ++ct) bc[ct] = bias[ct * 16 + m];

    float ps[8], pq[8];
#pragma unroll
    for (int ct = 0; ct < 8; ++ct) { ps[ct] = 0.f; pq[ct] = 0.f; }

    __syncthreads();  // s_sum/s_sq init visible before any flush

    const int NT = NN / 16;              // 6250, exact
    const int stride = gridDim.x * 4;    // waves total
    int t = blockIdx.x * 4 + w;

    const unsigned short* abase = hin + (size_t)m * 128 + q * 8;

    int4 ra[4];
    if (t < NT) {
        const unsigned short* ap = abase + (size_t)t * (16 * 128);
#pragma unroll
        for (int kc = 0; kc < 4; ++kc) ra[kc] = *(const int4*)(ap + kc * 32);
    }

    while (t < NT) {
        // consume prefetched raw A into fragment regs
        bf16x8 a[4];
#pragma unroll
        for (int kc = 0; kc < 4; ++kc) { BF8 tt; tt.i4 = ra[kc]; a[kc] = tt.v; }

        // issue next tile's loads before compute (hidden under MFMA+stores)
        int tn = t + stride;
        if (tn < NT) {
            const unsigned short* ap = abase + (size_t)tn * (16 * 128);
#pragma unroll
            for (int kc = 0; kc < 4; ++kc) ra[kc] = *(const int4*)(ap + kc * 32);
        }

        floatx4 acc[8];
#pragma unroll
        for (int ct = 0; ct < 8; ++ct) acc[ct] = (floatx4)0.0f;
#pragma unroll
        for (int kc = 0; kc < 4; ++kc)
#pragma unroll
            for (int ct = 0; ct < 8; ++ct)
                acc[ct] = __builtin_amdgcn_mfma_f32_16x16x32_bf16(a[kc], wf[ct][kc], acc[ct], 0, 0, 0);

        // epilogue: bias, store y (row = t*16 + q*4 + i, col = ct*16 + m)
        float* yb = y + (size_t)(t * 16 + q * 4) * 128 + m;
#pragma unroll
        for (int ct = 0; ct < 8; ++ct) {
#pragma unroll
            for (int i = 0; i < 4; ++i) {
                float yv = acc[ct][i] + bc[ct];
                yb[(size_t)i * 128 + ct * 16] = yv;
                ps[ct] += yv;
                pq[ct] += yv * yv;
            }
        }
        t = tn;
    }

    // flush register stats: LDS reduce, then 2 global atomics per column
#pragma unroll
    for (int ct = 0; ct < 8; ++ct) {
        atomicAdd(&s_sum[ct * 16 + m], ps[ct]);
        atomicAdd(&s_sq[ct * 16 + m], pq[ct]);
    }
    __syncthreads();
    if (tid < 128) {
        unsafeAtomicAdd(&statsOut[tid], s_sum[tid]);
        unsafeAtomicAdd(&statsOut[128 + tid], s_sq[tid]);
    }
}

// ---------------------------------------------------------------------------
// BN(train, biased var) + ReLU.  OUT_BF16: write bf16 (h1) else fp32 in place
// ---------------------------------------------------------------------------
template <int OUT_BF16>
__global__ __launch_bounds__(256) void bn_relu_k(
    const float* __restrict__ y, const float* __restrict__ stats,
    const float* __restrict__ g, const float* __restrict__ beta,
    float* outf, unsigned short* __restrict__ outh) {
    __shared__ __align__(16) float sc[128];
    __shared__ __align__(16) float sh[128];
    int t = threadIdx.x;
    if (t < 128) {
        const float inv = 1.0f / (float)NN;
        float mean = stats[t] * inv;
        float var = stats[128 + t] * inv - mean * mean;
        float s = g[t] * rsqrtf(var + 1e-5f);
        sc[t] = s;
        sh[t] = beta[t] - mean * s;
    }
    __syncthreads();
    const int total4 = NN * 32;
    const float4* y4 = (const float4*)y;
    for (int i = blockIdx.x * 256 + t; i < total4; i += gridDim.x * 256) {
        int c4 = i & 31;
        float4 v = y4[i];
        float4 s = ((const float4*)sc)[c4];
        float4 b = ((const float4*)sh)[c4];
        float r0 = fmaxf(v.x * s.x + b.x, 0.f);
        float r1 = fmaxf(v.y * s.y + b.y, 0.f);
        float r2 = fmaxf(v.z * s.z + b.z, 0.f);
        float r3 = fmaxf(v.w * s.w + b.w, 0.f);
        if (OUT_BF16) {
            ushort4 u;
            u.x = f2bf(r0); u.y = f2bf(r1); u.z = f2bf(r2); u.w = f2bf(r3);
            ((ushort4*)outh)[i] = u;
        } else {
            ((float4*)outf)[i] = make_float4(r0, r1, r2, r3);
        }
    }
}

// ---------------------------------------------------------------------------
extern "C" void kernel_launch(void* const* d_in, const int* in_sizes, int n_in,
                              void* d_out, int out_size, void* d_ws, size_t ws_size,
                              hipStream_t stream) {
    const float* x   = (const float*)d_in[0];
    const int* ei    = (const int*)d_in[1];   // int64 in ref -> int32 from harness
    const float* eps = (const float*)d_in[2];
    const float* W1  = (const float*)d_in[3];
    const float* b1  = (const float*)d_in[4];
    const float* g1  = (const float*)d_in[5];
    const float* be1 = (const float*)d_in[6];
    const float* W2  = (const float*)d_in[7];
    const float* b2  = (const float*)d_in[8];
    const float* g2  = (const float*)d_in[9];
    const float* be2 = (const float*)d_in[10];
    float* out = (float*)d_out;

    // Workspace (~29.5 MB): [csr][hbuf bf16 25.6MB][stats 2KB][wbf 64KB]
    // gemm1 writes y1 to d_out; bn_relu<1> out->hbuf; gemm2 hbuf->out; bn2 in place.
    int* deg        = (int*)d_ws;           // NPAD
    int* offs       = deg + NPAD;           // NPAD
    int* cursor     = offs + NPAD;          // NPAD
    int* chunkSums  = cursor + NPAD;        // 512
    int* ssrc       = chunkSums + 512;      // EE + pad
    unsigned short* hbuf = (unsigned short*)(ssrc + EE + 256);   // N*D bf16
    float* stats    = (float*)(hbuf + (size_t)NN * DD);          // 512
    unsigned short* wbf = (unsigned short*)(stats + 512);        // 2*128*128 bf16

    hipMemsetAsync(deg, 0, NPAD * sizeof(int), stream);
    hipMemsetAsync(stats, 0, 512 * sizeof(float), stream);

    const int numChunks = (NN + 255) / 256;  // 391
    hist_k<<<(EE + 255) / 256, 256, 0, stream>>>(ei, deg);
    scan1_k<<<numChunks, 256, 0, stream>>>(deg, offs, chunkSums);
    scan2_k<<<1, 512, 0, stream>>>(chunkSums, numChunks);
    scan3_k<<<numChunks, 256, 0, stream>>>(offs, chunkSums, cursor);
    esort_k<<<(EE + 255) / 256, 256, 0, stream>>>(ei, cursor, ssrc);
    aggregate_k<<<(NN * 32 + 255) / 256, 256, 0, stream>>>(
        (const float4*)x, ssrc, offs, deg, eps, (ushort4*)hbuf);
    wconv_k<<<32, 256, 0, stream>>>(W1, W2, wbf);

    const int gblocks = 512;  // ~2 blocks/CU, persistent grid-stride
    gin_gemm_k<<<gblocks, 256, 0, stream>>>(hbuf, wbf, b1, out, stats);
    bn_relu_k<1><<<4096, 256, 0, stream>>>(out, stats, g1, be1, nullptr, hbuf);
    gin_gemm_k<<<gblocks, 256, 0, stream>>>(hbuf, wbf + 16384, b2, out, stats + 256);
    bn_relu_k<0><<<4096, 256, 0, stream>>>(out, stats + 256, g2, be2, out, nullptr);
}